// Round 9
// baseline (632.854 us; speedup 1.0000x reference)
//
#include <hip/hip_runtime.h>
#include <math.h>

#define N 4096
#define E 96
#define H 6
#define DH 16
#define G 64
#define CMAX 128          // max supported group size (mean 64, +8 sigma safe)
#define KSTR 20           // 20 floats = 80 B rows: 16B-aligned b128, 8 words/bank (min)
#define NW 8              // waves per block
#define NT 512            // threads per block

typedef __attribute__((address_space(3))) unsigned int       lds_u32_t;
typedef const __attribute__((address_space(1))) unsigned int glb_u32_t;

// One block per (group, head, position-parity); 768 blocks, 2 resident/CU.
// feats rows are gathered into LDS via async global_load_lds (zero VGPR
// pressure -> no spills, loads fully in flight), qkv reads LDS only.
// Per-row rotation (6*(row&3) float4-chunks) is applied on the GLOBAL source
// address at staging so the 4 row-quarters read disjoint LDS bank groups.
__global__ __launch_bounds__(NT, 4) void fused_kernel(const float* __restrict__ feats,
                                                      const int* __restrict__ grp,
                                                      const float* __restrict__ w_in,
                                                      const float* __restrict__ b_in,
                                                      const float* __restrict__ w_out,
                                                      const float* __restrict__ w_cls,
                                                      float* __restrict__ part) {
    __shared__ float wl[48 * 100];        // w_in head slice (48 cols x 96), stride 100
    __shared__ float feats_c[64 * 96];    // 24 KB staged feats chunk (rotated layout)
    __shared__ float kh[CMAX * KSTR];
    __shared__ float vh[CMAX * KSTR];     // zero-filled; rows < cnt overwritten
    __shared__ float qh[64 * KSTR];       // own-parity q rows, compact index j = r>>1
    __shared__ float ps[NW * CMAX];       // per-wave softmax weights
    __shared__ int   bucket[CMAX];
    __shared__ unsigned long long smask[64];
    __shared__ int   scount[64];
    __shared__ int   soffs[64];
    __shared__ float wfh[DH];
    __shared__ int   scnt;

    int g  = blockIdx.x & 63;
    int hh = blockIdx.x >> 6;             // 0..11
    int h  = hh >> 1;
    int hb = hh & 1;                      // position parity this block owns
    int tid = threadIdx.x, lane = tid & 63, wv = tid >> 6;

    // ---- Phase A: per-chunk ballot masks (deterministic)
    #pragma unroll
    for (int c8 = 0; c8 < 8; ++c8) {
        int cc = wv * 8 + c8;
        bool mt = (grp[(cc << 6) + lane] == g);
        unsigned long long mask = __ballot(mt);
        if (lane == 0) { smask[cc] = mask; scount[cc] = __popcll(mask); }
    }

    // ---- stage w_in slice: {q,k,v} x 16 cols for this head
    for (int idx = tid; idx < 48 * 24; idx += NT) {
        int ci = idx / 24, j = idx % 24;
        int pp = ci >> 4, dd = ci & 15;
        int gcol = pp * E + h * DH + dd;
        *(float4*)(wl + ci * 100 + j * 4) = *(const float4*)(w_in + gcol * E + j * 4);
    }

    // ---- head slice of folded classifier
    if (wv == 7) {
        int dd = lane & 15, u4 = lane >> 4;
        float s = 0.f;
        for (int u = u4 * 24; u < u4 * 24 + 24; ++u)
            s += w_cls[u] * w_out[u * E + h * DH + dd];
        s += __shfl_xor(s, 16, 64);
        s += __shfl_xor(s, 32, 64);
        if (lane < DH) wfh[lane] = s;
    }
    __syncthreads();

    // ---- Phase B: wave 0 scans chunk counts; waves 1..7 zero-fill vh
    if (wv == 0) {
        int v = scount[lane];
        int x = v;
        #pragma unroll
        for (int o = 1; o < 64; o <<= 1) {
            int y = __shfl_up(x, o, 64);
            if (lane >= o) x += y;
        }
        soffs[lane] = x - v;
        if (lane == 63) scnt = x;
    } else {
        for (int idx = tid - 64; idx < CMAX * KSTR; idx += NT - 64) vh[idx] = 0.f;
    }
    __syncthreads();

    int cnt = scnt; if (cnt > CMAX) cnt = CMAX;
    if (cnt == 0) return;                 // uniform per block

    // ---- Phase C: deterministic scatter (identical in both parity blocks)
    #pragma unroll
    for (int c8 = 0; c8 < 8; ++c8) {
        int cc = wv * 8 + c8;
        unsigned long long mask = smask[cc];
        if ((mask >> lane) & 1ULL) {
            int pos = soffs[cc] + __popcll(mask & ((1ULL << lane) - 1ULL));
            if (pos < CMAX) bucket[pos] = (cc << 6) + lane;
        }
    }
    __syncthreads();

    int d = tid & 15, rr = tid >> 4;      // rr 0..31
    float bq = b_in[h * DH + d];
    float bk = b_in[E + h * DH + d];
    float bv = b_in[2 * E + h * DH + d];
    const float4* wq  = (const float4*)(wl + d * 100);
    const float4* wk  = (const float4*)(wl + (16 + d) * 100);
    const float4* wvp = (const float4*)(wl + (32 + d) * 100);
    int rotq = 6 * (rr & 3);              // read-side rotation for this thread's rows

    #pragma unroll 1
    for (int cb = 0; cb < CMAX; cb += 64) {
        if (cb >= cnt) break;             // uniform

        // ---- async-stage 64 bucket rows into feats_c (rotated layout)
        #pragma unroll
        for (int t = 0; t < 3; ++t) {
            int u   = (wv * 3 + t) * 64 + lane;   // 16B unit, 0..1535
            int row = u / 24;                     // 0..63
            int ch  = u - row * 24;
            int e4s = ch - 6 * (row & 3);
            if (e4s < 0) e4s += 24;
            int rg = cb + row;
            int br = bucket[rg < cnt ? rg : 0];
            const float* src = feats + br * E + e4s * 4;
            __builtin_amdgcn_global_load_lds((glb_u32_t*)src,
                (lds_u32_t*)(feats_c + (wv * 3 + t) * 256), 16, 0, 0);
        }
        __syncthreads();                  // drains vmcnt (barrier semantics)

        // ---- qkv for slots cb+rr and cb+rr+32 from LDS
        int s0g = cb + rr, s1g = cb + rr + 32;
        const float* f0 = feats_c + rr * 96;
        const float* f1 = feats_c + (rr + 32) * 96;
        float q0 = 0.f, k0 = 0.f, v0 = 0.f;
        float q1 = 0.f, k1 = 0.f, v1 = 0.f;
        #pragma unroll
        for (int t = 0; t < 24; ++t) {
            int c = rotq + t; if (c >= 24) c -= 24;
            float4 x0 = *(const float4*)(f0 + c * 4);
            float4 x1 = *(const float4*)(f1 + c * 4);
            float4 a = wq[t], b = wk[t], cw = wvp[t];
            q0 += x0.x*a.x + x0.y*a.y + x0.z*a.z + x0.w*a.w;
            k0 += x0.x*b.x + x0.y*b.y + x0.z*b.z + x0.w*b.w;
            v0 += x0.x*cw.x + x0.y*cw.y + x0.z*cw.z + x0.w*cw.w;
            q1 += x1.x*a.x + x1.y*a.y + x1.z*a.z + x1.w*a.w;
            k1 += x1.x*b.x + x1.y*b.y + x1.z*b.z + x1.w*b.w;
            v1 += x1.x*cw.x + x1.y*cw.y + x1.z*cw.z + x1.w*cw.w;
        }
        if (s0g < cnt) {
            kh[s0g * KSTR + d] = k0 + bk;
            vh[s0g * KSTR + d] = v0 + bv;
            if ((s0g & 1) == hb) qh[(s0g >> 1) * KSTR + d] = (q0 + bq) * 0.25f;
        }
        if (s1g < cnt) {
            kh[s1g * KSTR + d] = k1 + bk;
            vh[s1g * KSTR + d] = v1 + bv;
            if ((s1g & 1) == hb) qh[(s1g >> 1) * KSTR + d] = (q1 + bq) * 0.25f;
        }
        __syncthreads();                  // reads done before restage / attention
    }

    // ---- attention: wave wv handles compact rows j = wv, wv+8, ...
    for (int j = wv; 2 * j + hb < cnt; j += NW) {
        int r = 2 * j + hb;
        const float4* q4 = (const float4*)(qh + j * KSTR);      // broadcast
        float4 qa = q4[0], qb = q4[1], qc = q4[2], qd = q4[3];

        const float4* k4 = (const float4*)(kh + lane * KSTR);
        float4 ka = k4[0], kb = k4[1], kc = k4[2], kd = k4[3];
        float d0 = qa.x*ka.x + qa.y*ka.y + qa.z*ka.z + qa.w*ka.w;
        float d1 = qb.x*kb.x + qb.y*kb.y + qb.z*kb.z + qb.w*kb.w;
        float d2 = qc.x*kc.x + qc.y*kc.y + qc.z*kc.z + qc.w*kc.w;
        float d3 = qd.x*kd.x + qd.y*kd.y + qd.z*kd.z + qd.w*kd.w;
        float a0 = (d0 + d1) + (d2 + d3);
        float s0v = (lane < cnt) ? a0 : -INFINITY;
        float s1v = -INFINITY;
        if (cnt > 64) {
            const float4* k4b = (const float4*)(kh + (64 + lane) * KSTR);
            float4 ea = k4b[0], eb = k4b[1], ec = k4b[2], ed = k4b[3];
            float e0 = qa.x*ea.x + qa.y*ea.y + qa.z*ea.z + qa.w*ea.w;
            float e1 = qb.x*eb.x + qb.y*eb.y + qb.z*eb.z + qb.w*eb.w;
            float e2 = qc.x*ec.x + qc.y*ec.y + qc.z*ec.z + qc.w*ec.w;
            float e3 = qd.x*ed.x + qd.y*ed.y + qd.z*ed.z + qd.w*ed.w;
            float a1 = (e0 + e1) + (e2 + e3);
            s1v = (64 + lane < cnt) ? a1 : -INFINITY;
        }

        float m = fmaxf(s0v, s1v);
        #pragma unroll
        for (int o = 32; o >= 1; o >>= 1) m = fmaxf(m, __shfl_xor(m, o, 64));
        float p0 = __expf(s0v - m);
        float p1 = (cnt > 64) ? __expf(s1v - m) : 0.f;
        float l = p0 + p1;
        #pragma unroll
        for (int o = 32; o >= 1; o >>= 1) l += __shfl_xor(l, o, 64);
        ps[wv * CMAX + lane] = p0;
        ps[wv * CMAX + 64 + lane] = p1;

        // PV: fixed-trip, fully unrolled; ps==0 / vh==0 cover padding
        int mm4 = lane >> 4, dd = lane & 15;
        float acc = 0.f;
        #pragma unroll
        for (int k = 0; k < 16; ++k) {
            int m2 = mm4 + 4 * k;
            acc += ps[wv * CMAX + m2] * vh[m2 * KSTR + dd];
        }
        if (cnt > 64) {
            #pragma unroll
            for (int k = 16; k < 32; ++k) {
                int m2 = mm4 + 4 * k;
                acc += ps[wv * CMAX + m2] * vh[m2 * KSTR + dd];
            }
        }
        acc += __shfl_xor(acc, 16, 64);
        acc += __shfl_xor(acc, 32, 64);

        // partial logit for this head
        float pt = (acc / l) * wfh[dd];
        pt += __shfl_xor(pt, 1, 64);
        pt += __shfl_xor(pt, 2, 64);
        pt += __shfl_xor(pt, 4, 64);
        pt += __shfl_xor(pt, 8, 64);
        if (lane == 0) part[bucket[r] * 8 + h] = pt;    // exactly-once, no atomic
    }
}

// ---------------- K2: sum 6 head partials + folded bias, sigmoid
__global__ __launch_bounds__(512) void sigmoid_kernel(const float* __restrict__ part,
                                                      const float* __restrict__ w_cls,
                                                      const float* __restrict__ b_out,
                                                      const float* __restrict__ b_cls,
                                                      float* __restrict__ out) {
    __shared__ float sbias;
    int tid = threadIdx.x;
    if (tid < 64) {
        float s = w_cls[tid] * b_out[tid];
        if (tid < 32) s += w_cls[tid + 64] * b_out[tid + 64];
        #pragma unroll
        for (int o = 32; o >= 1; o >>= 1) s += __shfl_xor(s, o, 64);
        if (tid == 0) sbias = s + b_cls[0];
    }
    __syncthreads();
    int i = blockIdx.x * 512 + tid;
    const float4* p = (const float4*)(part + i * 8);
    float4 u = p[0], v = p[1];
    float s = u.x + u.y + u.z + u.w + v.x + v.y + sbias;
    out[i] = 1.f / (1.f + __expf(-s));
}

extern "C" void kernel_launch(void* const* d_in, const int* in_sizes, int n_in,
                              void* d_out, int out_size, void* d_ws, size_t ws_size,
                              hipStream_t stream) {
    const float* feats = (const float*)d_in[0];
    const int*   grp   = (const int*)  d_in[1];
    const float* w_in  = (const float*)d_in[2];
    const float* b_in  = (const float*)d_in[3];
    const float* w_out = (const float*)d_in[4];
    const float* b_out = (const float*)d_in[5];
    const float* w_cls = (const float*)d_in[6];
    const float* b_cls = (const float*)d_in[7];
    float* out = (float*)d_out;

    float* part = (float*)d_ws;           // N*8 floats, every (row,head<6) slot written

    fused_kernel<<<G * H * 2, NT, 0, stream>>>(feats, grp, w_in, b_in, w_out, w_cls, part);
    sigmoid_kernel<<<N / 512, 512, 0, stream>>>(part, w_cls, b_out, b_cls, out);
}

// Round 10
// 100.598 us; speedup vs baseline: 6.2909x; 6.2909x over previous
//
#include <hip/hip_runtime.h>
#include <math.h>

#define N 4096
#define E 96
#define H 6
#define DH 16
#define G 64
#define CMAX 128          // max supported group size (mean 64, +8 sigma safe)
#define KSTR 19           // LDS row stride for kh/vh/qh (r6-proven)
#define FSTR 104          // bf16 elems per staged row (96 + 8 pad): 208 B, 16B-aligned
#define NW 8              // waves per block
#define NT 512            // threads per block

typedef __attribute__((ext_vector_type(8))) short short8;   // 8 bf16 in 4 VGPRs
typedef __attribute__((ext_vector_type(4))) float f32x4;

static __device__ __forceinline__ unsigned short f2bf(float f) {
    unsigned u = __builtin_bit_cast(unsigned, f);
    return (unsigned short)((u + 0x7fffu + ((u >> 16) & 1u)) >> 16);   // RNE
}
static __device__ __forceinline__ unsigned pack2(float lo, float hi) {
    return (unsigned)f2bf(lo) | ((unsigned)f2bf(hi) << 16);
}

// One block per (group, head, position-parity); structure identical to the
// 46 us r6 kernel EXCEPT the qkv phase, which is now MFMA over bf16-staged
// feats (r2-validated fragment layouts). Deterministic bucket build so both
// parity blocks compute identical bucket arrays.
__global__ __launch_bounds__(NT, 4) void fused_kernel(const float* __restrict__ feats,
                                                      const int* __restrict__ grp,
                                                      const float* __restrict__ w_in,
                                                      const float* __restrict__ b_in,
                                                      const float* __restrict__ w_out,
                                                      const float* __restrict__ w_cls,
                                                      float* __restrict__ part) {
    __shared__ short fA[CMAX * FSTR];     // 26.6 KB staged feats rows (bf16)
    __shared__ short wB[48 * FSTR];       // 10 KB w_in head slice (bf16), row = part*16+dd
    __shared__ float bia[48];
    __shared__ float kh[CMAX * KSTR];
    __shared__ float vh[CMAX * KSTR];     // zero-filled; rows < cnt overwritten
    __shared__ float qh[64 * KSTR];       // own-parity q rows, compact index j = r>>1
    __shared__ float ps[NW * CMAX];       // per-wave softmax weights
    __shared__ int   bucket[CMAX];
    __shared__ unsigned long long smask[64];
    __shared__ int   scount[64];
    __shared__ int   soffs[64];
    __shared__ float wfh[DH];             // head slice of folded classifier
    __shared__ int   scnt;

    int g  = blockIdx.x & 63;
    int hh = blockIdx.x >> 6;             // 0..11
    int h  = hh >> 1;
    int hb = hh & 1;                      // position parity this block owns
    int tid = threadIdx.x, lane = tid & 63, wv = tid >> 6;

    // ---- Phase A: per-chunk ballot masks (deterministic)
    #pragma unroll
    for (int c8 = 0; c8 < 8; ++c8) {
        int cc = wv * 8 + c8;
        bool mt = (grp[(cc << 6) + lane] == g);
        unsigned long long mask = __ballot(mt);
        if (lane == 0) { smask[cc] = mask; scount[cc] = __popcll(mask); }
    }

    // ---- stage wB (bf16) + bia + wfh (disjoint thread ranges)
    if (tid < 384) {
        int row = tid >> 3, seg = tid & 7;          // row = part*16 + dd, seg: 12 floats
        int gcol = (row >> 4) * E + h * DH + (row & 15);
        const float4* src = (const float4*)(w_in + gcol * E + seg * 12);
        unsigned* dst = (unsigned*)(wB + row * FSTR + seg * 12);
        #pragma unroll
        for (int t = 0; t < 3; ++t) {
            float4 v = src[t];
            dst[2 * t]     = pack2(v.x, v.y);
            dst[2 * t + 1] = pack2(v.z, v.w);
        }
    } else if (tid < 432) {
        int c = tid - 384;
        bia[c] = b_in[(c >> 4) * E + h * DH + (c & 15)];
    } else if (wv == 7) {
        int dd = lane & 15, u4 = lane >> 4;
        float s = 0.f;
        for (int u = u4 * 24; u < u4 * 24 + 24; ++u)
            s += w_cls[u] * w_out[u * E + h * DH + dd];
        s += __shfl_xor(s, 16, 64);
        s += __shfl_xor(s, 32, 64);
        if (lane < DH) wfh[lane] = s;
    }
    __syncthreads();

    // ---- Phase B: wave 0 scans chunk counts; waves 1..7 zero-fill vh
    if (wv == 0) {
        int v = scount[lane];
        int x = v;
        #pragma unroll
        for (int o = 1; o < 64; o <<= 1) {
            int y = __shfl_up(x, o, 64);
            if (lane >= o) x += y;
        }
        soffs[lane] = x - v;
        if (lane == 63) scnt = x;
    } else {
        for (int idx = tid - 64; idx < CMAX * KSTR; idx += NT - 64) vh[idx] = 0.f;
    }
    __syncthreads();

    int cnt = scnt; if (cnt > CMAX) cnt = CMAX;

    // ---- Phase C: deterministic scatter (identical in both parity blocks)
    #pragma unroll
    for (int c8 = 0; c8 < 8; ++c8) {
        int cc = wv * 8 + c8;
        unsigned long long mask = smask[cc];
        if ((mask >> lane) & 1ULL) {
            int pos = soffs[cc] + __popcll(mask & ((1ULL << lane) - 1ULL));
            if (pos < CMAX) bucket[pos] = (cc << 6) + lane;
        }
    }
    __syncthreads();

    // ---- stage fA: group's feats rows as bf16 (6 float4 loads per thread)
    {
        int srow = tid >> 2, sq = tid & 3;          // row, quarter (24 floats)
        if (srow < cnt) {
            const float4* src = (const float4*)(feats + bucket[srow] * E + sq * 24);
            unsigned* dst = (unsigned*)(fA + srow * FSTR + sq * 24);
            #pragma unroll
            for (int t = 0; t < 6; ++t) {
                float4 v = src[t];
                dst[2 * t]     = pack2(v.x, v.y);
                dst[2 * t + 1] = pack2(v.z, v.w);
            }
        }
    }
    __syncthreads();

    // ---- MFMA qkv: jobs (rt, ct); D col=lane&15, row=(lane>>4)*4+r (m89-verified)
    {
        int lr = lane & 15, kg = lane >> 4;
        int njobs = ((cnt + 15) >> 4) * 3;
        for (int jj = wv; jj < njobs; jj += NW) {
            int rt = jj / 3;
            int ct = jj - rt * 3;                   // 0=q 1=k 2=v
            const short* ab = fA + (rt * 16 + lr) * FSTR + kg * 8;
            const short* bb = wB + (ct * 16 + lr) * FSTR + kg * 8;
            f32x4 acc = {0.f, 0.f, 0.f, 0.f};
            acc = __builtin_amdgcn_mfma_f32_16x16x32_bf16(*(const short8*)(ab),
                                                          *(const short8*)(bb), acc, 0, 0, 0);
            acc = __builtin_amdgcn_mfma_f32_16x16x32_bf16(*(const short8*)(ab + 32),
                                                          *(const short8*)(bb + 32), acc, 0, 0, 0);
            acc = __builtin_amdgcn_mfma_f32_16x16x32_bf16(*(const short8*)(ab + 64),
                                                          *(const short8*)(bb + 64), acc, 0, 0, 0);
            float bias = bia[ct * 16 + lr];
            #pragma unroll
            for (int r = 0; r < 4; ++r) {
                int row = rt * 16 + kg * 4 + r;
                if (row < cnt) {
                    float v = acc[r] + bias;
                    if (ct == 1)      kh[row * KSTR + lr] = v;
                    else if (ct == 2) vh[row * KSTR + lr] = v;
                    else if ((row & 1) == hb) qh[(row >> 1) * KSTR + lr] = v * 0.25f;
                }
            }
        }
    }
    __syncthreads();

    // ---- attention (verbatim r6): wave wv handles compact rows j = wv, wv+8, ...
    for (int j = wv; 2 * j + hb < cnt; j += NW) {
        int r = 2 * j + hb;
        float qv[16];
        #pragma unroll
        for (int e = 0; e < 16; ++e) qv[e] = qh[j * KSTR + e];   // broadcast

        float a0 = 0.f;
        #pragma unroll
        for (int e = 0; e < 16; ++e) a0 += qv[e] * kh[lane * KSTR + e];
        float s0 = (lane < cnt) ? a0 : -INFINITY;
        float s1 = -INFINITY;
        if (cnt > 64) {
            float a1 = 0.f;
            #pragma unroll
            for (int e = 0; e < 16; ++e) a1 += qv[e] * kh[(64 + lane) * KSTR + e];
            s1 = (64 + lane < cnt) ? a1 : -INFINITY;
        }

        float m = fmaxf(s0, s1);
        #pragma unroll
        for (int o = 32; o >= 1; o >>= 1) m = fmaxf(m, __shfl_xor(m, o, 64));
        float p0 = __expf(s0 - m);                      // masked lanes -> 0
        float p1 = (cnt > 64) ? __expf(s1 - m) : 0.f;
        float l = p0 + p1;
        #pragma unroll
        for (int o = 32; o >= 1; o >>= 1) l += __shfl_xor(l, o, 64);
        ps[wv * CMAX + lane] = p0;
        ps[wv * CMAX + 64 + lane] = p1;

        // PV: fixed-trip, fully unrolled; ps==0 / vh==0 cover padding
        int mm4 = lane >> 4, dd = lane & 15;
        float acc = 0.f;
        #pragma unroll
        for (int k = 0; k < 16; ++k) {
            int m2 = mm4 + 4 * k;
            acc += ps[wv * CMAX + m2] * vh[m2 * KSTR + dd];
        }
        if (cnt > 64) {
            #pragma unroll
            for (int k = 16; k < 32; ++k) {
                int m2 = mm4 + 4 * k;
                acc += ps[wv * CMAX + m2] * vh[m2 * KSTR + dd];
            }
        }
        acc += __shfl_xor(acc, 16, 64);
        acc += __shfl_xor(acc, 32, 64);

        // partial logit for this head
        float pt = (acc / l) * wfh[dd];
        pt += __shfl_xor(pt, 1, 64);
        pt += __shfl_xor(pt, 2, 64);
        pt += __shfl_xor(pt, 4, 64);
        pt += __shfl_xor(pt, 8, 64);
        if (lane == 0) part[bucket[r] * 8 + h] = pt;    // exactly-once write, no atomic
    }
}

// ---------------- K2: sum 6 head partials + folded bias, sigmoid
__global__ __launch_bounds__(512) void sigmoid_kernel(const float* __restrict__ part,
                                                      const float* __restrict__ w_cls,
                                                      const float* __restrict__ b_out,
                                                      const float* __restrict__ b_cls,
                                                      float* __restrict__ out) {
    __shared__ float sbias;
    int tid = threadIdx.x;
    if (tid < 64) {
        float s = w_cls[tid] * b_out[tid];
        if (tid < 32) s += w_cls[tid + 64] * b_out[tid + 64];
        #pragma unroll
        for (int o = 32; o >= 1; o >>= 1) s += __shfl_xor(s, o, 64);
        if (tid == 0) sbias = s + b_cls[0];
    }
    __syncthreads();
    int i = blockIdx.x * 512 + tid;
    const float4* p = (const float4*)(part + i * 8);
    float4 u = p[0], v = p[1];
    float s = u.x + u.y + u.z + u.w + v.x + v.y + sbias;
    out[i] = 1.f / (1.f + __expf(-s));
}

extern "C" void kernel_launch(void* const* d_in, const int* in_sizes, int n_in,
                              void* d_out, int out_size, void* d_ws, size_t ws_size,
                              hipStream_t stream) {
    const float* feats = (const float*)d_in[0];
    const int*   grp   = (const int*)  d_in[1];
    const float* w_in  = (const float*)d_in[2];
    const float* b_in  = (const float*)d_in[3];
    const float* w_out = (const float*)d_in[4];
    const float* b_out = (const float*)d_in[5];
    const float* w_cls = (const float*)d_in[6];
    const float* b_cls = (const float*)d_in[7];
    float* out = (float*)d_out;

    float* part = (float*)d_ws;           // N*8 floats, every (row,head<6) slot written

    fused_kernel<<<G * H * 2, NT, 0, stream>>>(feats, grp, w_in, b_in, w_out, w_cls, part);
    sigmoid_kernel<<<N / 512, 512, 0, stream>>>(part, w_cls, b_out, b_cls, out);
}